// Round 8
// baseline (321.363 us; speedup 1.0000x reference)
//
#include <hip/hip_runtime.h>
#include <hip/hip_bf16.h>
#include <stdint.h>

typedef unsigned short u16;
typedef __bf16 bf16_t;
typedef bf16_t bf16x8 __attribute__((ext_vector_type(8)));
typedef float f32x4 __attribute__((ext_vector_type(4)));
typedef short short8 __attribute__((ext_vector_type(8)));
typedef short short4v __attribute__((ext_vector_type(4)));
typedef u16 u16x4 __attribute__((ext_vector_type(4)));

#define C_EMBD 768
#define NHEAD 12
#define HD 64
#define SEQ 4096
#define BATCH 2
#define M_TOK (BATCH * SEQ)   // 8192
#define N_QKV (3 * C_EMBD)    // 2304

__device__ __forceinline__ u16 f2bf(float f) {
  return __builtin_bit_cast(u16, (bf16_t)f);
}
__device__ __forceinline__ bf16x8 ld8(const u16* p) {
  return __builtin_bit_cast(bf16x8, *reinterpret_cast<const short8*>(p));
}
__device__ __forceinline__ void async16(const u16* g, u16* l) {
  __builtin_amdgcn_global_load_lds(
      (__attribute__((address_space(1))) void*)g,
      (__attribute__((address_space(3))) void*)l, 16, 0, 0);
}

#define MFMA32(a, b, c) __builtin_amdgcn_mfma_f32_16x16x32_bf16(a, b, c, 0, 0, 0)

__device__ __forceinline__ f32x4 mfma16(short4v a, short4v b, f32x4 c) {
#if __has_builtin(__builtin_amdgcn_mfma_f32_16x16x16bf16_1k)
  return __builtin_amdgcn_mfma_f32_16x16x16bf16_1k(a, b, c, 0, 0, 0);
#else
  asm volatile("v_mfma_f32_16x16x16_bf16 %0, %1, %2, %0"
               : "+v"(c) : "v"(a), "v"(b));
  return c;
#endif
}

// ---------------- fp32 -> bf16 convert (x) ----------------
__global__ __launch_bounds__(256) void k_convert(const float* __restrict__ in,
                                                 u16* __restrict__ out, int n4) {
  int i = blockIdx.x * blockDim.x + threadIdx.x;
  int stride = gridDim.x * blockDim.x;
  for (; i < n4; i += stride) {
    float4 v = reinterpret_cast<const float4*>(in)[i];
    u16x4 o;
    o.x = f2bf(v.x); o.y = f2bf(v.y); o.z = f2bf(v.z); o.w = f2bf(v.w);
    reinterpret_cast<u16x4*>(out)[i] = o;
  }
}

// ------------- transpose + convert weights: W[R][C] -> WT[C][R] bf16 -------------
__global__ __launch_bounds__(256) void k_tconv(const float* __restrict__ W,
                                               u16* __restrict__ WT, int R, int C) {
  __shared__ float t[32][33];
  int c0 = blockIdx.x * 32, r0 = blockIdx.y * 32;
  int tid = threadIdx.x;
  int a = tid >> 3, b = (tid & 7) * 4;
  float4 v = *reinterpret_cast<const float4*>(W + (size_t)(r0 + a) * C + c0 + b);
  t[a][b] = v.x; t[a][b + 1] = v.y; t[a][b + 2] = v.z; t[a][b + 3] = v.w;
  __syncthreads();
  u16x4 o;
  o.x = f2bf(t[b + 0][a]); o.y = f2bf(t[b + 1][a]);
  o.z = f2bf(t[b + 2][a]); o.w = f2bf(t[b + 3][a]);
  *reinterpret_cast<u16x4*>(WT + (size_t)(c0 + a) * R + r0 + b) = o;
}

// ------------- GEMM: C[M,N] = A[M,K] * Bt[N,K]^T + bias -------------
template <int MODE>
__global__ __launch_bounds__(256) void k_gemm(const u16* __restrict__ A,
                                              const u16* __restrict__ Bt,
                                              const float* __restrict__ bias,
                                              u16* __restrict__ q_out,
                                              u16* __restrict__ k_out,
                                              u16* __restrict__ v_out,
                                              float* __restrict__ fout, int K) {
  __shared__ __align__(16) u16 lA[128 * 32];
  __shared__ __align__(16) u16 lB[128 * 32];
  int tid = threadIdx.x;
  int bm = blockIdx.x, bn = blockIdx.y;
  int w = tid >> 6, l = tid & 63;
  int wr = w >> 1, wc = w & 1;
  int lrow = l & 15, lk = (l >> 4) * 8;
  f32x4 acc[4][4] = {};

  int srow = tid >> 2, scol = (tid & 3) * 8;
  const u16* gA0 = A + (size_t)(bm * 128 + srow) * K + scol;
  const u16* gA1 = A + (size_t)(bm * 128 + 64 + srow) * K + scol;
  const u16* gB0 = Bt + (size_t)(bn * 128 + srow) * K + scol;
  const u16* gB1 = Bt + (size_t)(bn * 128 + 64 + srow) * K + scol;
  u16* lA0 = lA + w * 512;
  u16* lA1 = lA + 2048 + w * 512;
  u16* lB0 = lB + w * 512;
  u16* lB1 = lB + 2048 + w * 512;

  for (int k0 = 0; k0 < K; k0 += 32) {
    __syncthreads();
    async16(gA0 + k0, lA0);
    async16(gA1 + k0, lA1);
    async16(gB0 + k0, lB0);
    async16(gB1 + k0, lB1);
    __syncthreads();
    bf16x8 af[4], bfr[4];
#pragma unroll
    for (int mf = 0; mf < 4; ++mf)
      af[mf] = ld8(&lA[(wr * 64 + mf * 16 + lrow) * 32 + lk]);
#pragma unroll
    for (int nf = 0; nf < 4; ++nf)
      bfr[nf] = ld8(&lB[(wc * 64 + nf * 16 + lrow) * 32 + lk]);
#pragma unroll
    for (int mf = 0; mf < 4; ++mf)
#pragma unroll
      for (int nf = 0; nf < 4; ++nf)
        acc[mf][nf] = __builtin_amdgcn_mfma_f32_16x16x32_bf16(
            af[mf], bfr[nf], acc[mf][nf], 0, 0, 0);
  }

#pragma unroll
  for (int nf = 0; nf < 4; ++nf) {
    int col = bn * 128 + wc * 64 + nf * 16 + lrow;
    float bv = bias[col];
#pragma unroll
    for (int mf = 0; mf < 4; ++mf) {
      int row0 = bm * 128 + wr * 64 + mf * 16 + (l >> 4) * 4;
#pragma unroll
      for (int r = 0; r < 4; ++r) {
        float val = acc[mf][nf][r] + bv;
        int row = row0 + r;
        if constexpr (MODE == 0) {
          int which = (col >= 2 * C_EMBD) ? 2 : ((col >= C_EMBD) ? 1 : 0);
          int wi = col - which * C_EMBD;
          int head = wi >> 6, dd = wi & 63;
          int b = row >> 12, n = row & 4095;
          if (which == 2) {
            v_out[(((size_t)b * NHEAD + head) * HD + dd) * SEQ + n] = f2bf(val);
          } else {
            u16* dst = (which == 0) ? q_out : k_out;
            dst[(((size_t)b * NHEAD + head) * SEQ + n) * HD + dd] = f2bf(val);
          }
        } else {
          fout[(size_t)row * C_EMBD + col] = val;
        }
      }
    }
  }
}

// ------------- attention helpers -------------
#define CE_CONST (0.125f * 1.44269504088896f)  // scale * log2(e)

__device__ __forceinline__ void mask_diag(f32x4 (&s4)[4], int qrow, int t, int g) {
  int kb = 64 * t + 4 * g;
#pragma unroll
  for (int kvf = 0; kvf < 4; ++kvf)
#pragma unroll
    for (int r = 0; r < 4; ++r)
      if (kb + 16 * kvf + r > qrow) s4[kvf][r] = -1e30f;
}

__device__ __forceinline__ void process1(f32x4 (&s4)[4], float& mst, float& lsum,
                                         f32x4 (&o)[4], short4v (&pb)[4],
                                         bool diag, int qrow, int t, int g) {
  if (diag) mask_diag(s4, qrow, t, g);
  f32x4 mx = s4[0];
#pragma unroll
  for (int kvf = 1; kvf < 4; ++kvf)
#pragma unroll
    for (int r = 0; r < 4; ++r) mx[r] = fmaxf(mx[r], s4[kvf][r]);
  float rmax = fmaxf(fmaxf(mx[0], mx[1]), fmaxf(mx[2], mx[3]));
  rmax = fmaxf(rmax, __shfl_xor(rmax, 16));
  rmax = fmaxf(rmax, __shfl_xor(rmax, 32));
  bool keep = __all(rmax <= mst + 44.0f);  // defer-max: P bounded by ~2^8
  float mnew = keep ? mst : fmaxf(mst, rmax);
  float mCE = mnew * CE_CONST;
  float rs = 0.f;
#pragma unroll
  for (int kvf = 0; kvf < 4; ++kvf) {
    f32x4 pf;
#pragma unroll
    for (int r = 0; r < 4; ++r) {
      pf[r] = exp2f(s4[kvf][r] * CE_CONST - mCE);
      pb[kvf][r] = (short)f2bf(pf[r]);
    }
    rs += (pf[0] + pf[1]) + (pf[2] + pf[3]);
  }
  rs += __shfl_xor(rs, 16);
  rs += __shfl_xor(rs, 32);
  if (keep) {
    lsum += rs;
  } else {
    float sc = exp2f((mst - mnew) * CE_CONST);
    lsum = lsum * sc + rs;
#pragma unroll
    for (int df = 0; df < 4; ++df) o[df] *= sc;
    mst = mnew;
  }
}

__device__ __forceinline__ void store16(u16* __restrict__ O, const f32x4 (&o)[4],
                                        float ssum, int b, int h, int q, int g) {
  float inv = 1.0f / ssum;
  size_t base = ((size_t)b * SEQ + q) * C_EMBD + h * HD;
#pragma unroll
  for (int df = 0; df < 4; ++df) {
    u16x4 pk;
#pragma unroll
    for (int r = 0; r < 4; ++r) pk[r] = f2bf(o[df][r] * inv);
    *reinterpret_cast<u16x4*>(&O[base + df * 16 + 4 * g]) = pk;
  }
}

// ------------- causal flash attention, 8-wave blocks, full wave occupancy ----
// 768 blocks = 24 bh x 32 q-tiles of 128 rows, LPT order (big tiles first).
// 8 waves x 16 q-rows share each K/V tile: staging per wave halves, barrier
// amortized 8-way. VGPR<=64 + 32KB LDS -> 4 blocks/CU = 32 waves/CU (cap),
// hiding the serial QK->softmax->PV chain that stalled the 4-wave version.
__global__ __launch_bounds__(512, 8) void k_attn(const u16* __restrict__ Q,
                                                 const u16* __restrict__ Kb,
                                                 const u16* __restrict__ VTb,
                                                 u16* __restrict__ O) {
  int blk = blockIdx.x;
  int qt = 31 - (blk / 24);        // LPT: big tiles first
  int bh = blk % 24;               // consecutive blocks -> different bh
  const u16* Qh = Q + (size_t)bh * SEQ * HD;
  const u16* Kh = Kb + (size_t)bh * SEQ * HD;
  const u16* Vh = VTb + (size_t)bh * HD * SEQ;  // [64][4096]
  int tid = threadIdx.x, w = tid >> 6, l = tid & 63;
  int i = l & 15, g = l >> 4;

  __shared__ __align__(16) u16 lK[2][64 * 64];
  __shared__ __align__(16) u16 lV[2][64 * 64];

  int qwb = qt * 128 + w * 16;     // wave's q-row base
  int qr = qwb + i;
  bf16x8 qf0 = ld8(Qh + (size_t)qr * HD + g * 8);
  bf16x8 qf1 = ld8(Qh + (size_t)qr * HD + 32 + g * 8);
  f32x4 o[4] = {};
  float mst = -1e30f, lsum = 0.f;

  // staging: 512 threads x (1 K-chunk + 1 V-chunk) of 16B
  int r0 = tid >> 3, c0 = tid & 7;
  int cs0 = c0 ^ (r0 & 7);
  const u16* gK0 = Kh + r0 * HD + 8 * cs0;
  const u16* gV0 = Vh + (size_t)r0 * SEQ + 8 * cs0;
  int dst0 = 64 * r0 + 8 * c0;

  // hoisted fragment addresses (u16 indices into 64x64 swizzled tile)
  int koff0 = 64 * i + 8 * (g ^ (i & 7));
  int koff1 = 64 * i + 8 * ((g + 4) ^ (i & 7));
  int kvx = (i >> 1) & 3;
  int vbit = ((g >> 1) ^ (i & 1));
  int voff[4];
#pragma unroll
  for (int kvf = 0; kvf < 4; ++kvf)
    voff[kvf] = 64 * i + 8 * ((2 * (kvf ^ kvx)) | vbit) + 4 * (g & 1);

  {  // prologue: stage tile 0
    short8 a = *(const short8*)gK0;
    short8 c = *(const short8*)gV0;
    *(short8*)&lK[0][dst0] = a;
    *(short8*)&lV[0][dst0] = c;
  }
  __syncthreads();

  const int NT = 2 * qt + 2;
  int cur = 0;
  short8 ka, va;
  for (int t = 0; t < NT; ++t) {
    bool more = (t + 1 < NT);
    if (more) {  // issue next tile's global loads early
      ka = *(const short8*)(gK0 + (t + 1) * 64 * HD);
      va = *(const short8*)(gV0 + (t + 1) * 64);
    }
    const u16* lKb = lK[cur];
    const u16* lVb = lV[cur];
    f32x4 s4[4] = {};
    __builtin_amdgcn_s_setprio(1);
#pragma unroll
    for (int kvf = 0; kvf < 4; ++kvf) {
      bf16x8 kf0 = ld8(&lKb[koff0 + 1024 * kvf]);
      bf16x8 kf1 = ld8(&lKb[koff1 + 1024 * kvf]);
      s4[kvf] = MFMA32(kf0, qf0, s4[kvf]);
      s4[kvf] = MFMA32(kf1, qf1, s4[kvf]);
    }
    __builtin_amdgcn_s_setprio(0);
    short4v pb[4];
    bool diag = (64 * t + 63 > qwb);  // exact per-element mask inside
    process1(s4, mst, lsum, o, pb, diag, qr, t, g);
    __builtin_amdgcn_s_setprio(1);
#pragma unroll
    for (int df = 0; df < 4; ++df)
#pragma unroll
      for (int kvf = 0; kvf < 4; ++kvf) {
        short4v vf = *reinterpret_cast<const short4v*>(&lVb[voff[kvf] + 1024 * df]);
        o[df] = mfma16(vf, pb[kvf], o[df]);
      }
    __builtin_amdgcn_s_setprio(0);
    if (more) {
      u16* nK = lK[cur ^ 1];
      u16* nV = lV[cur ^ 1];
      *(short8*)&nK[dst0] = ka;
      *(short8*)&nV[dst0] = va;
      __syncthreads();
    }
    cur ^= 1;
  }
  int b = bh / NHEAD, h = bh % NHEAD;
  store16(O, o, lsum, b, h, qr, g);
}

extern "C" void kernel_launch(void* const* d_in, const int* in_sizes, int n_in,
                              void* d_out, int out_size, void* d_ws, size_t ws_size,
                              hipStream_t stream) {
  const float* x = (const float*)d_in[0];
  const float* W_attn = (const float*)d_in[1];
  const float* b_attn = (const float*)d_in[2];
  const float* W_out = (const float*)d_in[3];
  const float* b_out = (const float*)d_in[4];
  float* out = (float*)d_out;

  char* ws = (char*)d_ws;
  u16* xb = (u16*)(ws + 0);              // 8192*768*2       = 12,582,912
  u16* waT = (u16*)(ws + 12582912);      // 2304*768*2       =  3,538,944
  u16* woT = (u16*)(ws + 16121856);      // 768*768*2        =  1,179,648
  u16* q = (u16*)(ws + 17301504);        // 12,582,912
  u16* kk = (u16*)(ws + 29884416);       // 12,582,912
  u16* v = (u16*)(ws + 42467328);        // 12,582,912  (transposed [b][h][d][n])
  u16* ao = (u16*)(ws + 67633152);       // 12,582,912  (end 80,216,064)

  k_convert<<<1536, 256, 0, stream>>>(x, xb, M_TOK * C_EMBD / 4);
  k_tconv<<<dim3(N_QKV / 32, C_EMBD / 32), 256, 0, stream>>>(W_attn, waT, C_EMBD, N_QKV);
  k_tconv<<<dim3(C_EMBD / 32, C_EMBD / 32), 256, 0, stream>>>(W_out, woT, C_EMBD, C_EMBD);
  k_gemm<0><<<dim3(M_TOK / 128, N_QKV / 128), 256, 0, stream>>>(
      xb, waT, b_attn, q, kk, v, nullptr, C_EMBD);
  k_attn<<<768, 512, 0, stream>>>(q, kk, v, ao);
  k_gemm<1><<<dim3(M_TOK / 128, C_EMBD / 128), 256, 0, stream>>>(
      ao, woT, b_out, nullptr, nullptr, nullptr, out, C_EMBD);
}

// Round 9
// 292.468 us; speedup vs baseline: 1.0988x; 1.0988x over previous
//
#include <hip/hip_runtime.h>
#include <hip/hip_bf16.h>
#include <stdint.h>

typedef unsigned short u16;
typedef __bf16 bf16_t;
typedef bf16_t bf16x8 __attribute__((ext_vector_type(8)));
typedef float f32x4 __attribute__((ext_vector_type(4)));
typedef short short8 __attribute__((ext_vector_type(8)));
typedef short short4v __attribute__((ext_vector_type(4)));
typedef u16 u16x4 __attribute__((ext_vector_type(4)));

#define C_EMBD 768
#define NHEAD 12
#define HD 64
#define SEQ 4096
#define BATCH 2
#define M_TOK (BATCH * SEQ)   // 8192
#define N_QKV (3 * C_EMBD)    // 2304

__device__ __forceinline__ u16 f2bf(float f) {
  return __builtin_bit_cast(u16, (bf16_t)f);
}
__device__ __forceinline__ bf16x8 ld8(const u16* p) {
  return __builtin_bit_cast(bf16x8, *reinterpret_cast<const short8*>(p));
}
__device__ __forceinline__ void async16(const u16* g, u16* l) {
  __builtin_amdgcn_global_load_lds(
      (__attribute__((address_space(1))) void*)g,
      (__attribute__((address_space(3))) void*)l, 16, 0, 0);
}

#define MFMA32(a, b, c) __builtin_amdgcn_mfma_f32_16x16x32_bf16(a, b, c, 0, 0, 0)

__device__ __forceinline__ f32x4 mfma16(short4v a, short4v b, f32x4 c) {
#if __has_builtin(__builtin_amdgcn_mfma_f32_16x16x16bf16_1k)
  return __builtin_amdgcn_mfma_f32_16x16x16bf16_1k(a, b, c, 0, 0, 0);
#else
  asm volatile("v_mfma_f32_16x16x16_bf16 %0, %1, %2, %0"
               : "+v"(c) : "v"(a), "v"(b));
  return c;
#endif
}

// ---------------- fp32 -> bf16 convert (x) ----------------
__global__ __launch_bounds__(256) void k_convert(const float* __restrict__ in,
                                                 u16* __restrict__ out, int n4) {
  int i = blockIdx.x * blockDim.x + threadIdx.x;
  int stride = gridDim.x * blockDim.x;
  for (; i < n4; i += stride) {
    float4 v = reinterpret_cast<const float4*>(in)[i];
    u16x4 o;
    o.x = f2bf(v.x); o.y = f2bf(v.y); o.z = f2bf(v.z); o.w = f2bf(v.w);
    reinterpret_cast<u16x4*>(out)[i] = o;
  }
}

// ------------- transpose + convert weights: W[R][C] -> WT[C][R] bf16 -------------
__global__ __launch_bounds__(256) void k_tconv(const float* __restrict__ W,
                                               u16* __restrict__ WT, int R, int C) {
  __shared__ float t[32][33];
  int c0 = blockIdx.x * 32, r0 = blockIdx.y * 32;
  int tid = threadIdx.x;
  int a = tid >> 3, b = (tid & 7) * 4;
  float4 v = *reinterpret_cast<const float4*>(W + (size_t)(r0 + a) * C + c0 + b);
  t[a][b] = v.x; t[a][b + 1] = v.y; t[a][b + 2] = v.z; t[a][b + 3] = v.w;
  __syncthreads();
  u16x4 o;
  o.x = f2bf(t[b + 0][a]); o.y = f2bf(t[b + 1][a]);
  o.z = f2bf(t[b + 2][a]); o.w = f2bf(t[b + 3][a]);
  *reinterpret_cast<u16x4*>(WT + (size_t)(c0 + a) * R + r0 + b) = o;
}

// ------------- GEMM: C[M,N] = A[M,K] * Bt[N,K]^T + bias -------------
template <int MODE>
__global__ __launch_bounds__(256) void k_gemm(const u16* __restrict__ A,
                                              const u16* __restrict__ Bt,
                                              const float* __restrict__ bias,
                                              u16* __restrict__ q_out,
                                              u16* __restrict__ k_out,
                                              u16* __restrict__ v_out,
                                              float* __restrict__ fout, int K) {
  __shared__ __align__(16) u16 lA[128 * 32];
  __shared__ __align__(16) u16 lB[128 * 32];
  int tid = threadIdx.x;
  int bm = blockIdx.x, bn = blockIdx.y;
  int w = tid >> 6, l = tid & 63;
  int wr = w >> 1, wc = w & 1;
  int lrow = l & 15, lk = (l >> 4) * 8;
  f32x4 acc[4][4] = {};

  int srow = tid >> 2, scol = (tid & 3) * 8;
  const u16* gA0 = A + (size_t)(bm * 128 + srow) * K + scol;
  const u16* gA1 = A + (size_t)(bm * 128 + 64 + srow) * K + scol;
  const u16* gB0 = Bt + (size_t)(bn * 128 + srow) * K + scol;
  const u16* gB1 = Bt + (size_t)(bn * 128 + 64 + srow) * K + scol;
  u16* lA0 = lA + w * 512;
  u16* lA1 = lA + 2048 + w * 512;
  u16* lB0 = lB + w * 512;
  u16* lB1 = lB + 2048 + w * 512;

  for (int k0 = 0; k0 < K; k0 += 32) {
    __syncthreads();
    async16(gA0 + k0, lA0);
    async16(gA1 + k0, lA1);
    async16(gB0 + k0, lB0);
    async16(gB1 + k0, lB1);
    __syncthreads();
    bf16x8 af[4], bfr[4];
#pragma unroll
    for (int mf = 0; mf < 4; ++mf)
      af[mf] = ld8(&lA[(wr * 64 + mf * 16 + lrow) * 32 + lk]);
#pragma unroll
    for (int nf = 0; nf < 4; ++nf)
      bfr[nf] = ld8(&lB[(wc * 64 + nf * 16 + lrow) * 32 + lk]);
#pragma unroll
    for (int mf = 0; mf < 4; ++mf)
#pragma unroll
      for (int nf = 0; nf < 4; ++nf)
        acc[mf][nf] = __builtin_amdgcn_mfma_f32_16x16x32_bf16(
            af[mf], bfr[nf], acc[mf][nf], 0, 0, 0);
  }

#pragma unroll
  for (int nf = 0; nf < 4; ++nf) {
    int col = bn * 128 + wc * 64 + nf * 16 + lrow;
    float bv = bias[col];
#pragma unroll
    for (int mf = 0; mf < 4; ++mf) {
      int row0 = bm * 128 + wr * 64 + mf * 16 + (l >> 4) * 4;
#pragma unroll
      for (int r = 0; r < 4; ++r) {
        float val = acc[mf][nf][r] + bv;
        int row = row0 + r;
        if constexpr (MODE == 0) {
          int which = (col >= 2 * C_EMBD) ? 2 : ((col >= C_EMBD) ? 1 : 0);
          int wi = col - which * C_EMBD;
          int head = wi >> 6, dd = wi & 63;
          int b = row >> 12, n = row & 4095;
          if (which == 2) {
            v_out[(((size_t)b * NHEAD + head) * HD + dd) * SEQ + n] = f2bf(val);
          } else {
            u16* dst = (which == 0) ? q_out : k_out;
            dst[(((size_t)b * NHEAD + head) * SEQ + n) * HD + dd] = f2bf(val);
          }
        } else {
          fout[(size_t)row * C_EMBD + col] = val;
        }
      }
    }
  }
}

// ------------- attention helpers -------------
#define CE_CONST (0.125f * 1.44269504088896f)  // scale * log2(e)

__device__ __forceinline__ void mask_diag(f32x4 (&s4)[4], int qrow, int t, int g) {
  int kb = 64 * t + 4 * g;
#pragma unroll
  for (int kvf = 0; kvf < 4; ++kvf)
#pragma unroll
    for (int r = 0; r < 4; ++r)
      if (kb + 16 * kvf + r > qrow) s4[kvf][r] = -1e30f;
}

__device__ __forceinline__ void process1(f32x4 (&s4)[4], float& mst, float& lsum,
                                         f32x4 (&o)[4], short4v (&pb)[4],
                                         bool diag, int qrow, int t, int g) {
  if (diag) mask_diag(s4, qrow, t, g);
  f32x4 mx = s4[0];
#pragma unroll
  for (int kvf = 1; kvf < 4; ++kvf)
#pragma unroll
    for (int r = 0; r < 4; ++r) mx[r] = fmaxf(mx[r], s4[kvf][r]);
  float rmax = fmaxf(fmaxf(mx[0], mx[1]), fmaxf(mx[2], mx[3]));
  rmax = fmaxf(rmax, __shfl_xor(rmax, 16));
  rmax = fmaxf(rmax, __shfl_xor(rmax, 32));
  bool keep = __all(rmax <= mst + 44.0f);  // defer-max: P bounded by ~2^8
  float mnew = keep ? mst : fmaxf(mst, rmax);
  float mCE = mnew * CE_CONST;
  float rs = 0.f;
#pragma unroll
  for (int kvf = 0; kvf < 4; ++kvf) {
    f32x4 pf;
#pragma unroll
    for (int r = 0; r < 4; ++r) {
      pf[r] = exp2f(s4[kvf][r] * CE_CONST - mCE);
      pb[kvf][r] = (short)f2bf(pf[r]);
    }
    rs += (pf[0] + pf[1]) + (pf[2] + pf[3]);
  }
  rs += __shfl_xor(rs, 16);
  rs += __shfl_xor(rs, 32);
  if (keep) {
    lsum += rs;
  } else {
    float sc = exp2f((mst - mnew) * CE_CONST);
    lsum = lsum * sc + rs;
#pragma unroll
    for (int df = 0; df < 4; ++df) o[df] *= sc;
    mst = mnew;
  }
}

__device__ __forceinline__ void store16(u16* __restrict__ O, const f32x4 (&o)[4],
                                        float ssum, int b, int h, int q, int g) {
  float inv = 1.0f / ssum;
  size_t base = ((size_t)b * SEQ + q) * C_EMBD + h * HD;
#pragma unroll
  for (int df = 0; df < 4; ++df) {
    u16x4 pk;
#pragma unroll
    for (int r = 0; r < 4; ++r) pk[r] = f2bf(o[df][r] * inv);
    *reinterpret_cast<u16x4*>(&O[base + df * 16 + 4 * g]) = pk;
  }
}

// ------------- causal flash attention: 2 q-row-groups/wave, async staging ----
// 768 blocks = 24 bh x 32 q-tiles of 128 rows (LPT order). 4 waves x 32 rows
// (two 16-row groups A/B, B=A+64). Each K/V fragment read feeds BOTH groups'
// MFMAs -> LDS read traffic halves vs 16-row waves. Staging via
// global_load_lds (linear LDS dest = wave-uniform + lane*16; swizzle on the
// global SOURCE address), issued at iter top, drained by end-of-iter barrier.
__global__ __launch_bounds__(256, 4) void k_attn(const u16* __restrict__ Q,
                                                 const u16* __restrict__ Kb,
                                                 const u16* __restrict__ VTb,
                                                 u16* __restrict__ O) {
  int blk = blockIdx.x;
  int qt = 31 - (blk / 24);        // LPT: big tiles first
  int bh = blk % 24;
  const u16* Qh = Q + (size_t)bh * SEQ * HD;
  const u16* Kh = Kb + (size_t)bh * SEQ * HD;
  const u16* Vh = VTb + (size_t)bh * HD * SEQ;  // [64][4096]
  int tid = threadIdx.x, w = tid >> 6, l = tid & 63;
  int i = l & 15, g = l >> 4;

  __shared__ __align__(16) u16 lK[2][64 * 64];
  __shared__ __align__(16) u16 lV[2][64 * 64];

  int qA = 128 * qt + 16 * w + i;  // group A (first half of block rows)
  int qB = qA + 64;                // group B (second half)
  bf16x8 qfA0 = ld8(Qh + (size_t)qA * HD + g * 8);
  bf16x8 qfA1 = ld8(Qh + (size_t)qA * HD + 32 + g * 8);
  bf16x8 qfB0 = ld8(Qh + (size_t)qB * HD + g * 8);
  bf16x8 qfB1 = ld8(Qh + (size_t)qB * HD + 32 + g * 8);
  f32x4 oA[4] = {}, oB[4] = {};
  float mA = -1e30f, sA = 0.f, mB = -1e30f, sB = 0.f;

  // staging source addresses (pre-swizzled global; LDS dest linear 16*tid)
  int r0 = tid >> 3, c0 = tid & 7;
  int cs0 = c0 ^ (r0 & 7);         // (r0+32)&7 == r0&7 -> same swizzle
  const u16* gK0 = Kh + r0 * HD + 8 * cs0;
  const u16* gK1 = gK0 + 32 * HD;
  const u16* gV0 = Vh + (size_t)r0 * SEQ + 8 * cs0;
  const u16* gV1 = gV0 + 32 * SEQ;
  // wave-uniform LDS dest bases (u16 idx): lane*8 added by hardware
  int du = 512 * w;

  // fragment addresses (u16 indices into 64x64 swizzled tile)
  int koff0 = 64 * i + 8 * (g ^ (i & 7));
  int koff1 = 64 * i + 8 * ((g + 4) ^ (i & 7));
  int kvx = (i >> 1) & 3;
  int vbit = ((g >> 1) ^ (i & 1));
  int voff[4];
#pragma unroll
  for (int kvf = 0; kvf < 4; ++kvf)
    voff[kvf] = 64 * i + 8 * ((2 * (kvf ^ kvx)) | vbit) + 4 * (g & 1);

  // prologue: async-stage tile 0 into buf 0
  async16(gK0, &lK[0][du]);
  async16(gK1, &lK[0][2048 + du]);
  async16(gV0, &lV[0][du]);
  async16(gV1, &lV[0][2048 + du]);
  __syncthreads();

  const int NT = 2 * qt + 2;
  int cur = 0;
  for (int t = 0; t < NT; ++t) {
    if (t + 1 < NT) {  // async-stage next tile into other buffer (overlaps compute)
      int nb = cur ^ 1;
      async16(gK0 + (t + 1) * 64 * HD, &lK[nb][du]);
      async16(gK1 + (t + 1) * 64 * HD, &lK[nb][2048 + du]);
      async16(gV0 + (t + 1) * 64, &lV[nb][du]);
      async16(gV1 + (t + 1) * 64, &lV[nb][2048 + du]);
    }
    const u16* lKb = lK[cur];
    const u16* lVb = lV[cur];
    bool hasA = (t <= 2 * qt);     // A's KV range ends at tile 2qt (diag)
    f32x4 s4A[4] = {}, s4B[4] = {};
    __builtin_amdgcn_s_setprio(1);
#pragma unroll
    for (int kvf = 0; kvf < 4; ++kvf) {
      bf16x8 kf0 = ld8(&lKb[koff0 + 1024 * kvf]);
      bf16x8 kf1 = ld8(&lKb[koff1 + 1024 * kvf]);
      s4B[kvf] = MFMA32(kf0, qfB0, s4B[kvf]);
      s4B[kvf] = MFMA32(kf1, qfB1, s4B[kvf]);
      if (hasA) {
        s4A[kvf] = MFMA32(kf0, qfA0, s4A[kvf]);
        s4A[kvf] = MFMA32(kf1, qfA1, s4A[kvf]);
      }
    }
    __builtin_amdgcn_s_setprio(0);
    short4v pbB[4], pbA[4];
    process1(s4B, mB, sB, oB, pbB, t == NT - 1, qB, t, g);
    if (hasA) process1(s4A, mA, sA, oA, pbA, t == 2 * qt, qA, t, g);
    __builtin_amdgcn_s_setprio(1);
#pragma unroll
    for (int df = 0; df < 4; ++df)
#pragma unroll
      for (int kvf = 0; kvf < 4; ++kvf) {
        short4v vf = *reinterpret_cast<const short4v*>(&lVb[voff[kvf] + 1024 * df]);
        oB[df] = mfma16(vf, pbB[kvf], oB[df]);
        if (hasA) oA[df] = mfma16(vf, pbA[kvf], oA[df]);
      }
    __builtin_amdgcn_s_setprio(0);
    __syncthreads();  // drains async loads (next buf ready) + read-done fence
    cur ^= 1;
  }
  int b = bh / NHEAD, h = bh % NHEAD;
  store16(O, oB, sB, b, h, qB, g);
  store16(O, oA, sA, b, h, qA, g);
}

extern "C" void kernel_launch(void* const* d_in, const int* in_sizes, int n_in,
                              void* d_out, int out_size, void* d_ws, size_t ws_size,
                              hipStream_t stream) {
  const float* x = (const float*)d_in[0];
  const float* W_attn = (const float*)d_in[1];
  const float* b_attn = (const float*)d_in[2];
  const float* W_out = (const float*)d_in[3];
  const float* b_out = (const float*)d_in[4];
  float* out = (float*)d_out;

  char* ws = (char*)d_ws;
  u16* xb = (u16*)(ws + 0);              // 8192*768*2       = 12,582,912
  u16* waT = (u16*)(ws + 12582912);      // 2304*768*2       =  3,538,944
  u16* woT = (u16*)(ws + 16121856);      // 768*768*2        =  1,179,648
  u16* q = (u16*)(ws + 17301504);        // 12,582,912
  u16* kk = (u16*)(ws + 29884416);       // 12,582,912
  u16* v = (u16*)(ws + 42467328);        // 12,582,912  (transposed [b][h][d][n])
  u16* ao = (u16*)(ws + 67633152);       // 12,582,912  (end 80,216,064)

  k_convert<<<1536, 256, 0, stream>>>(x, xb, M_TOK * C_EMBD / 4);
  k_tconv<<<dim3(N_QKV / 32, C_EMBD / 32), 256, 0, stream>>>(W_attn, waT, C_EMBD, N_QKV);
  k_tconv<<<dim3(C_EMBD / 32, C_EMBD / 32), 256, 0, stream>>>(W_out, woT, C_EMBD, C_EMBD);
  k_gemm<0><<<dim3(M_TOK / 128, N_QKV / 128), 256, 0, stream>>>(
      xb, waT, b_attn, q, kk, v, nullptr, C_EMBD);
  k_attn<<<768, 256, 0, stream>>>(q, kk, v, ao);
  k_gemm<1><<<dim3(M_TOK / 128, C_EMBD / 128), 256, 0, stream>>>(
      ao, woT, b_out, nullptr, nullptr, nullptr, out, C_EMBD);
}

// Round 10
// 210.801 us; speedup vs baseline: 1.5245x; 1.3874x over previous
//
#include <hip/hip_runtime.h>
#include <hip/hip_bf16.h>
#include <stdint.h>

typedef unsigned short u16;
typedef __bf16 bf16_t;
typedef bf16_t bf16x8 __attribute__((ext_vector_type(8)));
typedef float f32x4 __attribute__((ext_vector_type(4)));
typedef short short8 __attribute__((ext_vector_type(8)));
typedef short short4v __attribute__((ext_vector_type(4)));
typedef u16 u16x4 __attribute__((ext_vector_type(4)));

#define C_EMBD 768
#define NHEAD 12
#define HD 64
#define SEQ 4096
#define BATCH 2
#define M_TOK (BATCH * SEQ)   // 8192
#define N_QKV (3 * C_EMBD)    // 2304

__device__ __forceinline__ u16 f2bf(float f) {
  return __builtin_bit_cast(u16, (bf16_t)f);
}
__device__ __forceinline__ bf16x8 ld8(const u16* p) {
  return __builtin_bit_cast(bf16x8, *reinterpret_cast<const short8*>(p));
}
__device__ __forceinline__ void async16(const u16* g, u16* l) {
  __builtin_amdgcn_global_load_lds(
      (__attribute__((address_space(1))) void*)g,
      (__attribute__((address_space(3))) void*)l, 16, 0, 0);
}

#define MFMA32(a, b, c) __builtin_amdgcn_mfma_f32_16x16x32_bf16(a, b, c, 0, 0, 0)

__device__ __forceinline__ f32x4 mfma16(short4v a, short4v b, f32x4 c) {
#if __has_builtin(__builtin_amdgcn_mfma_f32_16x16x16bf16_1k)
  return __builtin_amdgcn_mfma_f32_16x16x16bf16_1k(a, b, c, 0, 0, 0);
#else
  asm volatile("v_mfma_f32_16x16x16_bf16 %0, %1, %2, %0"
               : "+v"(c) : "v"(a), "v"(b));
  return c;
#endif
}

// ---------------- fp32 -> bf16 convert (x) ----------------
__global__ __launch_bounds__(256) void k_convert(const float* __restrict__ in,
                                                 u16* __restrict__ out, int n4) {
  int i = blockIdx.x * blockDim.x + threadIdx.x;
  int stride = gridDim.x * blockDim.x;
  for (; i < n4; i += stride) {
    float4 v = reinterpret_cast<const float4*>(in)[i];
    u16x4 o;
    o.x = f2bf(v.x); o.y = f2bf(v.y); o.z = f2bf(v.z); o.w = f2bf(v.w);
    reinterpret_cast<u16x4*>(out)[i] = o;
  }
}

// ------------- transpose + convert weights: W[R][C] -> WT[C][R] bf16 -------------
__global__ __launch_bounds__(256) void k_tconv(const float* __restrict__ W,
                                               u16* __restrict__ WT, int R, int C) {
  __shared__ float t[32][33];
  int c0 = blockIdx.x * 32, r0 = blockIdx.y * 32;
  int tid = threadIdx.x;
  int a = tid >> 3, b = (tid & 7) * 4;
  float4 v = *reinterpret_cast<const float4*>(W + (size_t)(r0 + a) * C + c0 + b);
  t[a][b] = v.x; t[a][b + 1] = v.y; t[a][b + 2] = v.z; t[a][b + 3] = v.w;
  __syncthreads();
  u16x4 o;
  o.x = f2bf(t[b + 0][a]); o.y = f2bf(t[b + 1][a]);
  o.z = f2bf(t[b + 2][a]); o.w = f2bf(t[b + 3][a]);
  *reinterpret_cast<u16x4*>(WT + (size_t)(c0 + a) * R + r0 + b) = o;
}

// ------------- GEMM: C[M,N] = A[M,K] * Bt[N,K]^T + bias -------------
template <int MODE>
__global__ __launch_bounds__(256) void k_gemm(const u16* __restrict__ A,
                                              const u16* __restrict__ Bt,
                                              const float* __restrict__ bias,
                                              u16* __restrict__ q_out,
                                              u16* __restrict__ k_out,
                                              u16* __restrict__ v_out,
                                              float* __restrict__ fout, int K) {
  __shared__ __align__(16) u16 lA[128 * 32];
  __shared__ __align__(16) u16 lB[128 * 32];
  int tid = threadIdx.x;
  int bm = blockIdx.x, bn = blockIdx.y;
  int w = tid >> 6, l = tid & 63;
  int wr = w >> 1, wc = w & 1;
  int lrow = l & 15, lk = (l >> 4) * 8;
  f32x4 acc[4][4] = {};

  int srow = tid >> 2, scol = (tid & 3) * 8;
  const u16* gA0 = A + (size_t)(bm * 128 + srow) * K + scol;
  const u16* gA1 = A + (size_t)(bm * 128 + 64 + srow) * K + scol;
  const u16* gB0 = Bt + (size_t)(bn * 128 + srow) * K + scol;
  const u16* gB1 = Bt + (size_t)(bn * 128 + 64 + srow) * K + scol;
  u16* lA0 = lA + w * 512;
  u16* lA1 = lA + 2048 + w * 512;
  u16* lB0 = lB + w * 512;
  u16* lB1 = lB + 2048 + w * 512;

  for (int k0 = 0; k0 < K; k0 += 32) {
    __syncthreads();
    async16(gA0 + k0, lA0);
    async16(gA1 + k0, lA1);
    async16(gB0 + k0, lB0);
    async16(gB1 + k0, lB1);
    __syncthreads();
    bf16x8 af[4], bfr[4];
#pragma unroll
    for (int mf = 0; mf < 4; ++mf)
      af[mf] = ld8(&lA[(wr * 64 + mf * 16 + lrow) * 32 + lk]);
#pragma unroll
    for (int nf = 0; nf < 4; ++nf)
      bfr[nf] = ld8(&lB[(wc * 64 + nf * 16 + lrow) * 32 + lk]);
#pragma unroll
    for (int mf = 0; mf < 4; ++mf)
#pragma unroll
      for (int nf = 0; nf < 4; ++nf)
        acc[mf][nf] = __builtin_amdgcn_mfma_f32_16x16x32_bf16(
            af[mf], bfr[nf], acc[mf][nf], 0, 0, 0);
  }

#pragma unroll
  for (int nf = 0; nf < 4; ++nf) {
    int col = bn * 128 + wc * 64 + nf * 16 + lrow;
    float bv = bias[col];
#pragma unroll
    for (int mf = 0; mf < 4; ++mf) {
      int row0 = bm * 128 + wr * 64 + mf * 16 + (l >> 4) * 4;
#pragma unroll
      for (int r = 0; r < 4; ++r) {
        float val = acc[mf][nf][r] + bv;
        int row = row0 + r;
        if constexpr (MODE == 0) {
          int which = (col >= 2 * C_EMBD) ? 2 : ((col >= C_EMBD) ? 1 : 0);
          int wi = col - which * C_EMBD;
          int head = wi >> 6, dd = wi & 63;
          int b = row >> 12, n = row & 4095;
          if (which == 2) {
            v_out[(((size_t)b * NHEAD + head) * HD + dd) * SEQ + n] = f2bf(val);
          } else {
            u16* dst = (which == 0) ? q_out : k_out;
            dst[(((size_t)b * NHEAD + head) * SEQ + n) * HD + dd] = f2bf(val);
          }
        } else {
          fout[(size_t)row * C_EMBD + col] = val;
        }
      }
    }
  }
}

// ------------- attention helpers -------------
#define CE_CONST (0.125f * 1.44269504088896f)  // scale * log2(e)

__device__ __forceinline__ void mask_diag(f32x4 (&s4)[4], int qrow, int t, int g) {
  int kb = 64 * t + 4 * g;
#pragma unroll
  for (int kvf = 0; kvf < 4; ++kvf)
#pragma unroll
    for (int r = 0; r < 4; ++r)
      if (kb + 16 * kvf + r > qrow) s4[kvf][r] = -1e30f;
}

// Softmax step with DEFERRED denominator: lsum is a PER-LANE partial sum.
// The rescale factor sc is row-uniform (rmax shfl'd across the row's 4 lanes,
// mst uniform by induction), so per-lane partials stay mutually consistent;
// the cross-lane row sum happens ONCE after the KV loop. Only the 2 rmax
// shfls remain on the per-tile critical path.
__device__ __forceinline__ void process1(f32x4 (&s4)[4], float& mst, float& lsum,
                                         f32x4 (&o)[4], short4v (&pb)[4],
                                         bool diag, int qrow, int t, int g) {
  if (diag) mask_diag(s4, qrow, t, g);
  f32x4 mx = s4[0];
#pragma unroll
  for (int kvf = 1; kvf < 4; ++kvf)
#pragma unroll
    for (int r = 0; r < 4; ++r) mx[r] = fmaxf(mx[r], s4[kvf][r]);
  float rmax = fmaxf(fmaxf(mx[0], mx[1]), fmaxf(mx[2], mx[3]));
  rmax = fmaxf(rmax, __shfl_xor(rmax, 16));
  rmax = fmaxf(rmax, __shfl_xor(rmax, 32));
  bool keep = __all(rmax <= mst + 44.0f);  // defer-max: P bounded by ~2^8
  float mnew = keep ? mst : fmaxf(mst, rmax);
  float mCE = mnew * CE_CONST;
  float rs = 0.f;
#pragma unroll
  for (int kvf = 0; kvf < 4; ++kvf) {
    f32x4 pf;
#pragma unroll
    for (int r = 0; r < 4; ++r) {
      pf[r] = exp2f(s4[kvf][r] * CE_CONST - mCE);
      pb[kvf][r] = (short)f2bf(pf[r]);
    }
    rs += (pf[0] + pf[1]) + (pf[2] + pf[3]);
  }
  if (keep) {
    lsum += rs;  // per-lane partial; no cross-lane shfl in the loop
  } else {
    float sc = exp2f((mst - mnew) * CE_CONST);
    lsum = lsum * sc + rs;
#pragma unroll
    for (int df = 0; df < 4; ++df) o[df] *= sc;
    mst = mnew;
  }
}

__device__ __forceinline__ void store16(u16* __restrict__ O, const f32x4 (&o)[4],
                                        float ssum, int b, int h, int q, int g) {
  float inv = 1.0f / ssum;
  size_t base = ((size_t)b * SEQ + q) * C_EMBD + h * HD;
#pragma unroll
  for (int df = 0; df < 4; ++df) {
    u16x4 pk;
#pragma unroll
    for (int r = 0; r < 4; ++r) pk[r] = f2bf(o[df][r] * inv);
    *reinterpret_cast<u16x4*>(&O[base + df * 16 + 4 * g]) = pk;
  }
}

// ------------- causal flash attention, async-staged, deferred denominator ---
// 1536 blocks = 24 bh x 64 q-tiles (LPT: qt=63 first). 4 waves x 16 q-rows,
// KVBLK=64 double-buffered. Staging via global_load_lds: LDS dest linear
// (wave-uniform 512*w + lane*16B), swizzle applied on the global SOURCE
// address; loads for t+1 issue at iter top, drain at the end-of-iter barrier.
// 5 blocks/CU (LDS 32KB, VGPR<=102) -> 20 waves/CU.
__global__ __launch_bounds__(256, 5) void k_attn(const u16* __restrict__ Q,
                                                 const u16* __restrict__ Kb,
                                                 const u16* __restrict__ VTb,
                                                 u16* __restrict__ O) {
  int blk = blockIdx.x;
  int qt = 63 - (blk / 24);        // LPT: big tiles first
  int bh = blk % 24;               // consecutive blocks -> different bh
  const u16* Qh = Q + (size_t)bh * SEQ * HD;
  const u16* Kh = Kb + (size_t)bh * SEQ * HD;
  const u16* Vh = VTb + (size_t)bh * HD * SEQ;  // [64][4096]
  int tid = threadIdx.x, w = tid >> 6, l = tid & 63;
  int i = l & 15, g = l >> 4;

  __shared__ __align__(16) u16 lK[2][64 * 64];
  __shared__ __align__(16) u16 lV[2][64 * 64];

  int qr = qt * 64 + w * 16 + i;
  bf16x8 qf0 = ld8(Qh + (size_t)qr * HD + g * 8);
  bf16x8 qf1 = ld8(Qh + (size_t)qr * HD + 32 + g * 8);
  f32x4 o[4] = {};
  float mst = -1e30f, lsum = 0.f;

  // staging source addresses (pre-swizzled global; LDS dest linear 8*tid u16)
  int r0 = tid >> 3, c0 = tid & 7;
  int cs0 = c0 ^ (r0 & 7);         // (r0+32)&7 == r0&7 -> same swizzle
  const u16* gK0 = Kh + r0 * HD + 8 * cs0;
  const u16* gK1 = gK0 + 32 * HD;
  const u16* gV0 = Vh + (size_t)r0 * SEQ + 8 * cs0;
  const u16* gV1 = gV0 + 32 * SEQ;
  int du = 512 * w;                // wave-uniform LDS base (u16 idx)

  // hoisted fragment addresses (u16 indices into 64x64 swizzled tile)
  int koff0 = 64 * i + 8 * (g ^ (i & 7));
  int koff1 = 64 * i + 8 * ((g + 4) ^ (i & 7));
  int kvx = (i >> 1) & 3;
  int vbit = ((g >> 1) ^ (i & 1));
  int voff[4];
#pragma unroll
  for (int kvf = 0; kvf < 4; ++kvf)
    voff[kvf] = 64 * i + 8 * ((2 * (kvf ^ kvx)) | vbit) + 4 * (g & 1);

  // prologue: async-stage tile 0 into buf 0
  async16(gK0, &lK[0][du]);
  async16(gK1, &lK[0][2048 + du]);
  async16(gV0, &lV[0][du]);
  async16(gV1, &lV[0][2048 + du]);
  __syncthreads();

  const int NT = qt + 1;
  int cur = 0;
  for (int t = 0; t < NT; ++t) {
    if (t + 1 < NT) {  // async-stage next tile (drains at end-of-iter barrier)
      int nb = cur ^ 1;
      async16(gK0 + (t + 1) * 64 * HD, &lK[nb][du]);
      async16(gK1 + (t + 1) * 64 * HD, &lK[nb][2048 + du]);
      async16(gV0 + (t + 1) * 64, &lV[nb][du]);
      async16(gV1 + (t + 1) * 64, &lV[nb][2048 + du]);
    }
    const u16* lKb = lK[cur];
    const u16* lVb = lV[cur];
    f32x4 s4[4] = {};
    __builtin_amdgcn_s_setprio(1);
#pragma unroll
    for (int kvf = 0; kvf < 4; ++kvf) {
      bf16x8 kf0 = ld8(&lKb[koff0 + 1024 * kvf]);
      bf16x8 kf1 = ld8(&lKb[koff1 + 1024 * kvf]);
      s4[kvf] = MFMA32(kf0, qf0, s4[kvf]);
      s4[kvf] = MFMA32(kf1, qf1, s4[kvf]);
    }
    __builtin_amdgcn_s_setprio(0);
    short4v pb[4];
    process1(s4, mst, lsum, o, pb, t == NT - 1, qr, t, g);
    __builtin_amdgcn_s_setprio(1);
#pragma unroll
    for (int df = 0; df < 4; ++df)
#pragma unroll
      for (int kvf = 0; kvf < 4; ++kvf) {
        short4v vf = *reinterpret_cast<const short4v*>(&lVb[voff[kvf] + 1024 * df]);
        o[df] = mfma16(vf, pb[kvf], o[df]);
      }
    __builtin_amdgcn_s_setprio(0);
    __syncthreads();  // read-done fence + drains the t+1 async loads
    cur ^= 1;
  }
  // one cross-lane row sum at the end (row = lanes {i, i+16, i+32, i+48})
  lsum += __shfl_xor(lsum, 16);
  lsum += __shfl_xor(lsum, 32);
  int b = bh / NHEAD, h = bh % NHEAD;
  store16(O, o, lsum, b, h, qr, g);
}

extern "C" void kernel_launch(void* const* d_in, const int* in_sizes, int n_in,
                              void* d_out, int out_size, void* d_ws, size_t ws_size,
                              hipStream_t stream) {
  const float* x = (const float*)d_in[0];
  const float* W_attn = (const float*)d_in[1];
  const float* b_attn = (const float*)d_in[2];
  const float* W_out = (const float*)d_in[3];
  const float* b_out = (const float*)d_in[4];
  float* out = (float*)d_out;

  char* ws = (char*)d_ws;
  u16* xb = (u16*)(ws + 0);              // 8192*768*2       = 12,582,912
  u16* waT = (u16*)(ws + 12582912);      // 2304*768*2       =  3,538,944
  u16* woT = (u16*)(ws + 16121856);      // 768*768*2        =  1,179,648
  u16* q = (u16*)(ws + 17301504);        // 12,582,912
  u16* kk = (u16*)(ws + 29884416);       // 12,582,912
  u16* v = (u16*)(ws + 42467328);        // 12,582,912  (transposed [b][h][d][n])
  u16* ao = (u16*)(ws + 67633152);       // 12,582,912  (end 80,216,064)

  k_convert<<<1536, 256, 0, stream>>>(x, xb, M_TOK * C_EMBD / 4);
  k_tconv<<<dim3(N_QKV / 32, C_EMBD / 32), 256, 0, stream>>>(W_attn, waT, C_EMBD, N_QKV);
  k_tconv<<<dim3(C_EMBD / 32, C_EMBD / 32), 256, 0, stream>>>(W_out, woT, C_EMBD, C_EMBD);
  k_gemm<0><<<dim3(M_TOK / 128, N_QKV / 128), 256, 0, stream>>>(
      xb, waT, b_attn, q, kk, v, nullptr, C_EMBD);
  k_attn<<<1536, 256, 0, stream>>>(q, kk, v, ao);
  k_gemm<1><<<dim3(M_TOK / 128, C_EMBD / 128), 256, 0, stream>>>(
      ao, woT, b_out, nullptr, nullptr, nullptr, out, C_EMBD);
}